// Round 5
// baseline (72.625 us; speedup 1.0000x reference)
//
#include <hip/hip_runtime.h>
#include <math.h>

#define BB 8
#define HH 256
#define WW 256
#define NPIX (BB*HH*WW)

// ws layout: [0] double part_sum[64] | [1024] float part_max[64] | [2048] int part_fg[64]
// Every slot written before read -> no init kernel.

// Read column `col`'s mask word w (64 rows) from LDS; inv -> complement (bg mask).
__device__ __forceinline__ unsigned long long ldsW(const unsigned* fmL, int col, int w, bool inv) {
    unsigned lo = fmL[col * 9 + 2 * w];
    unsigned hi = fmL[col * 9 + 2 * w + 1];
    unsigned long long v = ((unsigned long long)hi << 32) | lo;
    return inv ? ~v : v;
}

// Vertical distance from row i (word wi, bit bi) to nearest set bit of the
// class mask of column `col`, given the preloaded word cw = word wi.
// Exact; capped at 512 (= reference BIG).
__device__ __forceinline__ int vdist_rest(const unsigned* fmL, int col, int wi, int bi,
                                          unsigned long long cw, bool inv) {
    unsigned long long up = cw & (~0ull >> (63 - bi));   // bits at rows <= i
    unsigned long long dn = cw >> bi;                    // bits at rows >= i
    int du = 1 << 20, dd = 1 << 20;
    if (up) du = bi - (63 - __builtin_clzll(up));
    else {
        for (int w = wi - 1; w >= 0; --w) {
            unsigned long long v = ldsW(fmL, col, w, inv);
            if (v) { du = bi + ((wi - w) << 6) - (63 - __builtin_clzll(v)); break; }
        }
    }
    if (dn) dd = __builtin_ctzll(dn);
    else {
        for (int w = wi + 1; w < 4; ++w) {
            unsigned long long v = ldsW(fmL, col, w, inv);
            if (v) { dd = ((w - wi) << 6) - bi + __builtin_ctzll(v); break; }
        }
    }
    return min(min(du, dd), 512);
}

__device__ __forceinline__ int vdistL(const unsigned* fmL, int col, int wi, int bi, bool inv) {
    return vdist_rest(fmL, col, wi, bi, ldsW(fmL, col, wi, inv), inv);
}

// One block per (batch, 32-row stripe): 64 blocks x 1024 threads.
// Phase 1: build per-column 256-bit fg masks for the WHOLE batch in LDS
//          (coalesced loads, register partials, one fold, no atomics).
// Phase 2: per pixel, phi = isFg ? -dist_to_bg : +dist_to_fg via on-demand
//          bitmask vertical distances + pruned exact horizontal scan.
// Epilogue: per-block sum(phi*prob), max dist, fg flag (plain stores).
__global__ void __launch_bounds__(1024)
fused_edt(const int* __restrict__ tgt, const float* __restrict__ pred,
          double* __restrict__ part_sum, float* __restrict__ part_max,
          int* __restrict__ part_fg) {
    __shared__ unsigned partLds[256 * 33];   // [col][q(4)][w(8)] padded stride 33
    __shared__ unsigned fmL[256 * 9];        // folded masks, [col][8 words] pad 9
    __shared__ int wflag[16];
    __shared__ float wmaxL[16];
    __shared__ double wsumL[16];

    int t = threadIdx.x;
    int blk = blockIdx.x;
    int batch = blk >> 3;
    int i0 = (blk & 7) << 5;       // stripe rows [i0, i0+32)
    int j = t & 255;               // this thread's column (fixed)
    int q = t >> 8;                // row-phase 0..3

    // ---- Phase 1: build fg column-mask partials (coalesced: lanes -> consecutive j)
    const int* tbase = tgt + batch * (HH * WW) + j;
    #pragma unroll
    for (int w = 0; w < 8; ++w) {
        unsigned pw = 0;
        #pragma unroll
        for (int m = 0; m < 8; ++m) {
            int i = 32 * w + q + 4 * m;
            pw |= (tbase[i * WW] != 0 ? 1u : 0u) << (q + 4 * m);
        }
        partLds[j * 33 + q * 8 + w] = pw;
    }
    __syncthreads();

    // ---- fold 4 partials per (col, word): thread -> (col t>>2, word-pair t&3)
    {
        int jj = t >> 2, w2 = t & 3;
        int pb = jj * 33;
        unsigned lo = partLds[pb + 2 * w2]      | partLds[pb + 8 + 2 * w2]
                    | partLds[pb + 16 + 2 * w2] | partLds[pb + 24 + 2 * w2];
        unsigned hi = partLds[pb + 2 * w2 + 1]      | partLds[pb + 8 + 2 * w2 + 1]
                    | partLds[pb + 16 + 2 * w2 + 1] | partLds[pb + 24 + 2 * w2 + 1];
        fmL[jj * 9 + 2 * w2] = lo;
        fmL[jj * 9 + 2 * w2 + 1] = hi;
        unsigned long long bal = __ballot((lo | hi) != 0u);
        if ((t & 63) == 0) wflag[t >> 6] = (bal != 0ull);
    }
    __syncthreads();

    // ---- Phase 2: EDT + fused epilogue for this stripe (8 pixels/thread)
    const float* pbase = pred + batch * (HH * WW);
    double sd = 0.0;
    float mx = 0.0f;
    #pragma unroll
    for (int it = 0; it < 8; ++it) {
        int i = i0 + q + 4 * it;
        float x = pbase[i * WW + j];
        int wi = i >> 6, bi = i & 63;
        unsigned long long w0 = ldsW(fmL, j, wi, false);   // own fg word
        bool isFg = (w0 >> bi) & 1ull;
        unsigned long long cw = isFg ? ~w0 : w0;           // opposite-class word
        int d0 = vdist_rest(fmL, j, wi, bi, cw, isFg);
        float m = (float)(d0 * d0);
        for (int k = 1; k < WW; ++k) {
            float k2 = (float)(k * k);
            if (k2 >= m) break;                 // exact termination (monotone offsets)
            int jl = j - k; if (jl < 0) jl = 0;        // clamp is redundant-safe
            int jr = j + k; if (jr > 255) jr = 255;
            int dl = vdistL(fmL, jl, wi, bi, isFg);
            m = fminf(m, (float)(dl * dl) + k2);
            int dr = vdistL(fmL, jr, wi, bi, isFg);
            m = fminf(m, (float)(dr * dr) + k2);
        }
        float dist = sqrtf(m);
        float phi = isFg ? -dist : dist;
        float prob = 1.0f / (1.0f + expf(-x));
        sd += (double)(phi * prob);
        mx = fmaxf(mx, dist);
    }

    // ---- block reduce (16 waves)
    #pragma unroll
    for (int off = 32; off; off >>= 1) {
        mx = fmaxf(mx, __shfl_down(mx, off));
        sd += __shfl_down(sd, off);
    }
    if ((t & 63) == 0) { wmaxL[t >> 6] = mx; wsumL[t >> 6] = sd; }
    __syncthreads();
    if (t == 0) {
        float M = 0.0f; double S = 0.0; int F = 0;
        #pragma unroll
        for (int wv = 0; wv < 16; ++wv) {
            M = fmaxf(M, wmaxL[wv]); S += wsumL[wv]; F |= wflag[wv];
        }
        part_max[blk] = M; part_sum[blk] = S; part_fg[blk] = F;
    }
}

// One wave: fold 64 block-partials (8 per batch) -> scalar.
__global__ void reduce_out(const double* __restrict__ part_sum,
                           const float* __restrict__ part_max,
                           const int* __restrict__ part_fg,
                           float* __restrict__ out) {
    __shared__ double terms[8];
    int t = threadIdx.x;          // 64 threads; slot t; batch = t>>3
    double sd = part_sum[t];
    float mx = part_max[t];
    int fg = part_fg[t];
    #pragma unroll
    for (int off = 4; off; off >>= 1) {
        sd += __shfl_down(sd, off);
        mx = fmaxf(mx, __shfl_down(mx, off));
        fg |= __shfl_down(fg, off);
    }
    if ((t & 7) == 0) terms[t >> 3] = fg ? sd / ((double)mx + 1e-8) : 0.0;
    __syncthreads();
    if (t == 0) {
        double tot = 0.0;
        #pragma unroll
        for (int b = 0; b < BB; ++b) tot += terms[b];
        out[0] = (float)(tot / (double)NPIX);
    }
}

extern "C" void kernel_launch(void* const* d_in, const int* in_sizes, int n_in,
                              void* d_out, int out_size, void* d_ws, size_t ws_size,
                              hipStream_t stream) {
    const float* pred = (const float*)d_in[0];
    const int* tgt = (const int*)d_in[1];
    float* out = (float*)d_out;

    char* ws = (char*)d_ws;
    double* part_sum = (double*)ws;            // 64 doubles
    float* part_max = (float*)(ws + 1024);     // 64 floats
    int* part_fg = (int*)(ws + 2048);          // 64 ints

    fused_edt<<<64, 1024, 0, stream>>>(tgt, pred, part_sum, part_max, part_fg);
    reduce_out<<<1, 64, 0, stream>>>(part_sum, part_max, part_fg, out);
}

// Round 6
// 64.378 us; speedup vs baseline: 1.1281x; 1.1281x over previous
//
#include <hip/hip_runtime.h>
#include <math.h>

#define BB 8
#define HH 256
#define WW 256
#define NPIX (BB*HH*WW)
#define NROWS (BB*HH)   // 2048

// ws layout (byte offsets), every slot written before read (no init kernel):
//   [0]      float    part_max[2048]   per-row max dist
//   [8192]   double   part_sum[2048]   per-row sum(phi*prob)
//   [24576]  int      part_fg[2048]    per-row has-fg flag
//   [32768]  unsigned fg_words[8][8][256]  column fg bitmasks: word w of col j,
//                                          bit r = row 32*w + r  (64 KB total)

// k1: build column bitmasks, fully coalesced. Block = (batch, 32-row band).
__global__ void maskbuild(const int* __restrict__ tgt,
                          unsigned* __restrict__ fg_words) {
    int blk = blockIdx.x;            // b*8 + band
    int b = blk >> 3, band = blk & 7;
    int j = threadIdx.x;
    const int* base = tgt + b * (HH * WW) + (band * 32) * WW + j;
    unsigned bits = 0;
    #pragma unroll
    for (int r = 0; r < 32; ++r)
        bits |= (base[r * WW] != 0 ? 1u : 0u) << r;
    fg_words[b * 2048 + band * 256 + j] = bits;
}

// k2: one block per (b,i) row — same proven shape as R4's edt_fuse.
// Stage batch masks (8 KB, L2-hot) into LDS; per thread compute own-column
// vertical distances gF,gB ONCE from the bitmask (exact, capped 512);
// then R4's pruned exact horizontal scan + fused epilogue.
__global__ void edt_row(const unsigned* __restrict__ fg_words,
                        const float* __restrict__ pred,
                        float* __restrict__ part_max,
                        double* __restrict__ part_sum,
                        int* __restrict__ part_fg) {
    __shared__ unsigned maskL[256 * 9];   // [col][8 words], pad->stride 9 (2-way banks: free)
    __shared__ float sB[3 * WW];          // dist_to_bg^2 at WW+jp, 1e30 pads
    __shared__ float sF[3 * WW];          // dist_to_fg^2
    __shared__ float wmax[4];
    __shared__ double wsum[4];
    __shared__ int wfg[4];

    int row = blockIdx.x;                 // b*HH + i
    int b = row >> 8, i = row & 255;
    int j = threadIdx.x;

    float x = pred[row * WW + j];         // independent, issue early

    const unsigned* mb = fg_words + b * 2048;
    #pragma unroll
    for (int w = 0; w < 8; ++w)
        maskL[j * 9 + w] = mb[w * 256 + j];   // coalesced per w
    __syncthreads();

    // vertical distances for (i, col j) from the 256-bit column mask
    const int BIGI = 1 << 20;
    int pF = -BIGI, pB = -BIGI, nF = BIGI, nB = BIGI;
    #pragma unroll
    for (int w = 0; w < 4; ++w) {
        unsigned long long v = (unsigned long long)maskL[j * 9 + 2 * w]
                             | ((unsigned long long)maskL[j * 9 + 2 * w + 1] << 32);
        unsigned long long g = ~v;
        int d = i - 64 * w;               // my bit position within this word
        // bits at rows <= i
        unsigned long long bf = (d >= 63) ? v : ((d < 0) ? 0ull : (v & (~0ull >> (63 - d))));
        unsigned long long bb = (d >= 63) ? g : ((d < 0) ? 0ull : (g & (~0ull >> (63 - d))));
        if (bf) pF = 64 * w + 63 - __builtin_clzll(bf);   // w ascending => max
        if (bb) pB = 64 * w + 63 - __builtin_clzll(bb);
        // bits at rows >= i
        unsigned long long af = (d <= 0) ? v : ((d > 63) ? 0ull : (v & (~0ull << d)));
        unsigned long long ab = (d <= 0) ? g : ((d > 63) ? 0ull : (g & (~0ull << d)));
        if (af) nF = min(nF, 64 * w + __builtin_ctzll(af));
        if (ab) nB = min(nB, 64 * w + __builtin_ctzll(ab));
    }
    int gF = min(min(i - pF, nF - i), 512);   // dist to nearest fg (0 if own fg)
    int gB = min(min(i - pB, nB - i), 512);   // dist to nearest bg
    bool isFg = (gF == 0);
    unsigned long long fgb = __ballot(isFg);

    float fF = (float)gF, fB = (float)gB;
    sF[j] = 1e30f; sF[2 * WW + j] = 1e30f; sF[WW + j] = fF * fF;
    sB[j] = 1e30f; sB[2 * WW + j] = 1e30f; sB[WW + j] = fB * fB;
    __syncthreads();

    // pruned exact 1D EDT over the OPPOSITE class (own-class dist is 0)
    const float* sp = isFg ? sB : sF;
    float m = isFg ? fB * fB : fF * fF;
    int idx = WW + j;
    for (int k = 1; k < WW; ++k) {
        float k2 = (float)(k * k);
        if (k2 >= m) break;               // exact termination (monotone offsets)
        m = fminf(m, sp[idx - k] + k2);
        m = fminf(m, sp[idx + k] + k2);
    }
    float dist = sqrtf(m);
    float phi = isFg ? -dist : dist;
    float prob = 1.0f / (1.0f + expf(-x));
    double sd = (double)(phi * prob);
    float mx = dist;

    #pragma unroll
    for (int off = 32; off; off >>= 1) {
        mx = fmaxf(mx, __shfl_down(mx, off));
        sd += __shfl_down(sd, off);
    }
    int wid = j >> 6;
    if ((j & 63) == 0) { wmax[wid] = mx; wsum[wid] = sd; wfg[wid] = (fgb != 0ull); }
    __syncthreads();
    if (j == 0) {
        part_max[row] = fmaxf(fmaxf(wmax[0], wmax[1]), fmaxf(wmax[2], wmax[3]));
        part_sum[row] = wsum[0] + wsum[1] + wsum[2] + wsum[3];
        part_fg[row] = wfg[0] | wfg[1] | wfg[2] | wfg[3];
    }
}

// k3: one block, 4 waves; wave w folds batches 2w and 2w+1.
__global__ void reduce_out(const float* __restrict__ part_max,
                           const double* __restrict__ part_sum,
                           const int* __restrict__ part_fg,
                           float* __restrict__ out) {
    __shared__ double terms[8];
    int tx = threadIdx.x;
    int wv = tx >> 6, l = tx & 63;
    #pragma unroll
    for (int q = 0; q < 2; ++q) {
        int b = wv * 2 + q;
        int base = b * HH;
        float mx = fmaxf(fmaxf(part_max[base + l], part_max[base + l + 64]),
                         fmaxf(part_max[base + l + 128], part_max[base + l + 192]));
        double sd = part_sum[base + l] + part_sum[base + l + 64]
                  + part_sum[base + l + 128] + part_sum[base + l + 192];
        int fg = part_fg[base + l] | part_fg[base + l + 64]
               | part_fg[base + l + 128] | part_fg[base + l + 192];
        #pragma unroll
        for (int off = 32; off; off >>= 1) {
            mx = fmaxf(mx, __shfl_down(mx, off));
            sd += __shfl_down(sd, off);
            fg |= __shfl_down(fg, off);
        }
        if (l == 0) terms[b] = fg ? sd / ((double)mx + 1e-8) : 0.0;
    }
    __syncthreads();
    if (tx == 0) {
        double t = 0.0;
        #pragma unroll
        for (int b = 0; b < BB; ++b) t += terms[b];
        out[0] = (float)(t / (double)NPIX);
    }
}

extern "C" void kernel_launch(void* const* d_in, const int* in_sizes, int n_in,
                              void* d_out, int out_size, void* d_ws, size_t ws_size,
                              hipStream_t stream) {
    const float* pred = (const float*)d_in[0];
    const int* tgt = (const int*)d_in[1];
    float* out = (float*)d_out;

    char* ws = (char*)d_ws;
    float* part_max = (float*)ws;                  // 2048 floats
    double* part_sum = (double*)(ws + 8192);       // 2048 doubles
    int* part_fg = (int*)(ws + 24576);             // 2048 ints
    unsigned* fg_words = (unsigned*)(ws + 32768);  // 16384 u32 (64 KB)

    maskbuild<<<64, 256, 0, stream>>>(tgt, fg_words);
    edt_row<<<NROWS, WW, 0, stream>>>(fg_words, pred, part_max, part_sum, part_fg);
    reduce_out<<<1, 256, 0, stream>>>(part_max, part_sum, part_fg, out);
}